// Round 1
// baseline (77.524 us; speedup 1.0000x reference)
//
#include <hip/hip_runtime.h>
#include <math.h>

// Soft Bellman-Ford, sparsity-aware:
// R0 is a single 1.0 at start[b]; all values >= 0; support grows by <=1
// Manhattan step per iteration. After 50 iters, support is inside the
// 101x101 box centered at start. Compute only that window, in LDS.
constexpr int RADIUS   = 50;
constexpr int NITER    = 50;
constexpr int WSIZE    = 2 * RADIUS + 1;            // 101
constexpr int LDS_H    = WSIZE + 2;                 // 103 (zero halo)
constexpr int LDS_W    = WSIZE + 3;                 // 104 (pad, stride)
constexpr int NCELLS   = WSIZE * WSIZE;             // 10201
constexpr int NTHREADS = 1024;
constexpr int CPT      = (NCELLS + NTHREADS - 1) / NTHREADS;  // 10

__global__ __launch_bounds__(NTHREADS)
void sbf_window_kernel(const float* __restrict__ prob,
                       const int*   __restrict__ start,
                       const int*   __restrict__ goal,
                       float*       __restrict__ out,
                       int H, int W)
{
#pragma clang fp contract(off)
    __shared__ float R[LDS_H * LDS_W];   // 42848 B
    const int b   = blockIdx.x;
    const int tid = threadIdx.x;

    int sr = start[2 * b + 0]; sr = min(max(sr, 0), H - 1);
    int sc = start[2 * b + 1]; sc = min(max(sc, 0), W - 1);

    // Zero R (including halo; halo is never written again -> stays 0,
    // emulating both out-of-window zeros and SAME zero padding).
    for (int i = tid; i < LDS_H * LDS_W; i += NTHREADS) R[i] = 0.0f;

    // Per-thread cell setup. Strided mapping: cell idx = tid + k*NTHREADS
    // -> consecutive lanes touch consecutive LDS addresses (conflict-free)
    // and coalesced global p loads.
    int   off[CPT];   // LDS offsets (static-indexed via full unroll)
    float pv[CPT];    // probability_map values (loop-invariant, in regs)
    float nv[CPT];    // next values

    const float* pb = prob + (size_t)b * H * W;

#pragma unroll
    for (int k = 0; k < CPT; ++k) {
        int idx = tid + k * NTHREADS;
        if (idx < NCELLS) {
            int lr = idx / WSIZE;
            int lc = idx - lr * WSIZE;
            off[k] = (lr + 1) * LDS_W + (lc + 1);
            int gr = sr - RADIUS + lr;
            int gc = sc - RADIUS + lc;
            float p = 0.0f;
            // Out-of-grid cells get p = 0: R stays exactly 0 there forever,
            // which is exactly the reference's SAME zero padding behavior.
            if (gr >= 0 && gr < H && gc >= 0 && gc < W)
                p = pb[(size_t)gr * W + gc];
            pv[k] = p;
        } else {
            off[k] = 0;
            pv[k]  = 0.0f;
        }
    }

    __syncthreads();
    if (tid == 0) R[(RADIUS + 1) * LDS_W + (RADIUS + 1)] = 1.0f;  // R0[start]=1
    __syncthreads();

    for (int it = 0; it < NITER; ++it) {
        // Jacobi step: read all neighbors, compute into registers.
#pragma unroll
        for (int k = 0; k < CPT; ++k) {
            if (tid + k * NTHREADS < NCELLS) {
                int o = off[k];
                float up = R[o - LDS_W];
                float dn = R[o + LDS_W];
                float lf = R[o - 1];
                float rt = R[o + 1];
                float self = R[o];
                // kernel = cross/4; 0.25*x is exact, sum order is the only
                // reordering vs the reference conv.
                float nb = ((up + dn) + (lf + rt)) * 0.25f;
                float v  = self + nb * pv[k];          // no fma (contract off)
                v = fminf(fmaxf(v, 0.0f), 1.0f);       // clip(v, 0, 1)
                nv[k] = v;
            }
        }
        __syncthreads();
#pragma unroll
        for (int k = 0; k < CPT; ++k)
            if (tid + k * NTHREADS < NCELLS) R[off[k]] = nv[k];
        __syncthreads();
    }

    if (tid == 0) {
        int gr = goal[2 * b + 0]; gr = min(max(gr, 0), H - 1);
        int gc = goal[2 * b + 1]; gc = min(max(gc, 0), W - 1);
        int dr = gr - sr + RADIUS;
        int dc = gc - sc + RADIUS;
        float res = 0.0f;
        if (dr >= 0 && dr < WSIZE && dc >= 0 && dc < WSIZE)
            res = R[(dr + 1) * LDS_W + (dc + 1)];
        out[b] = res;   // exact 0 outside the box (and inside-box untouched
                        // cells hold exact 0 too, matching the reference)
    }
}

extern "C" void kernel_launch(void* const* d_in, const int* in_sizes, int n_in,
                              void* d_out, int out_size, void* d_ws, size_t ws_size,
                              hipStream_t stream)
{
    (void)n_in; (void)out_size; (void)d_ws; (void)ws_size;
    const float* prob  = (const float*)d_in[0];
    const int*   start = (const int*)d_in[1];
    const int*   goal  = (const int*)d_in[2];
    float*       out   = (float*)d_out;

    const int B  = in_sizes[1] / 2;                       // (B,2) coords
    const long long hw = (long long)in_sizes[0] / B;      // H*W
    const int H  = (int)(sqrt((double)hw) + 0.5);
    const int W  = H;

    sbf_window_kernel<<<dim3(B), dim3(NTHREADS), 0, stream>>>(
        prob, start, goal, out, H, W);
}

// Round 2
// 74.312 us; speedup vs baseline: 1.0432x; 1.0432x over previous
//
#include <hip/hip_runtime.h>
#include <math.h>

// Soft Bellman-Ford, register-patch version.
// - Support of R after t steps is the L1-ball of radius t around start, so
//   only the 101x101 window matters (50 iters), and a patch at L1 distance d
//   from start is exactly zero until iteration d-1  -> wave-granular skip.
// - Each thread owns a 4(w) x 8(h) patch of R and p in REGISTERS. LDS holds
//   only inter-patch boundary rows/cols, exchanged as aligned float4.
constexpr int RAD  = 50;
constexpr int NIT  = 50;
constexpr int PW   = 4;            // patch width  (cols)
constexpr int PH   = 8;            // patch height (rows)
constexpr int PC   = 26;           // patch grid cols -> 104 cols covered
constexpr int PR   = 13;           // patch grid rows -> 104 rows covered
constexpr int NACT = PC * PR;      // 338 worker threads
constexpr int NT   = 384;          // 6 waves
constexpr int SROW = 108;          // dword stride, bufTop/bufBot rows (104+4 pad, /4 odd)
constexpr int SCOL = 108;          // dword stride, bufL/bufR per patch-col

__global__ __launch_bounds__(NT)
void sbf_patch_kernel(const float* __restrict__ prob,
                      const int*   __restrict__ start,
                      const int*   __restrict__ goal,
                      float*       __restrict__ out,
                      int H, int W)
{
#pragma clang fp contract(off)
    __shared__ __align__(16) float bufTop[PR * SROW];  // row 0 of each patch
    __shared__ __align__(16) float bufBot[PR * SROW];  // row PH-1 of each patch
    __shared__ __align__(16) float bufL[PC * SCOL];    // col 0 of each patch, by global row
    __shared__ __align__(16) float bufR[PC * SCOL];    // col PW-1 of each patch

    const int b   = blockIdx.x;
    const int tid = threadIdx.x;

    const int sr = min(max(start[2*b+0], 0), H-1);
    const int sc = min(max(start[2*b+1], 0), W-1);

    for (int i = tid; i < PR*SROW; i += NT) { bufTop[i] = 0.f; bufBot[i] = 0.f; }
    for (int i = tid; i < PC*SCOL; i += NT) { bufL[i]  = 0.f; bufR[i]  = 0.f; }

    const bool valid = (tid < NACT);
    const int  pr = tid / PC;
    const int  pc = tid - pr * PC;
    const int  r0 = pr * PH;           // window-relative first row of patch
    const int  c0 = pc * PW;           // window-relative first col of patch

    float Rv[PH][PW];
    float pv[PH][PW];
#pragma unroll
    for (int r = 0; r < PH; ++r)
#pragma unroll
        for (int c = 0; c < PW; ++c) { Rv[r][c] = 0.f; pv[r][c] = 0.f; }

    if (valid) {
        const float* pb = prob + (size_t)b * H * W;
#pragma unroll
        for (int r = 0; r < PH; ++r) {
            const int gr = sr - RAD + r0 + r;
#pragma unroll
            for (int c = 0; c < PW; ++c) {
                const int gc = sc - RAD + c0 + c;
                // out-of-grid cells: p = 0 -> value stays exactly 0 forever,
                // reproducing SAME zero padding.
                if (gr >= 0 && gr < H && gc >= 0 && gc < W)
                    pv[r][c] = pb[(size_t)gr * W + gc];
            }
        }
    }

    // R0: single 1.0 at window center (50,50) -> patch (6,12), local (2,2).
    if (pr == RAD/PH && pc == RAD/PW) Rv[RAD%PH][RAD%PW] = 1.0f;

    // L1 distance from start to this patch's rectangle.
    const int drr  = max(0, max(r0 - RAD, RAD - (r0 + PH - 1)));
    const int dcc  = max(0, max(c0 - RAD, RAD - (c0 + PW - 1)));
    const int dist = drr + dcc;

    __syncthreads();   // LDS zero done

    if (valid) {       // publish R0 boundaries
        *(float4*)&bufTop[pr*SROW + c0] = make_float4(Rv[0][0], Rv[0][1], Rv[0][2], Rv[0][3]);
        *(float4*)&bufBot[pr*SROW + c0] = make_float4(Rv[PH-1][0], Rv[PH-1][1], Rv[PH-1][2], Rv[PH-1][3]);
        *(float4*)&bufL[pc*SCOL + r0    ] = make_float4(Rv[0][0], Rv[1][0], Rv[2][0], Rv[3][0]);
        *(float4*)&bufL[pc*SCOL + r0 + 4] = make_float4(Rv[4][0], Rv[5][0], Rv[6][0], Rv[7][0]);
        *(float4*)&bufR[pc*SCOL + r0    ] = make_float4(Rv[0][PW-1], Rv[1][PW-1], Rv[2][PW-1], Rv[3][PW-1]);
        *(float4*)&bufR[pc*SCOL + r0 + 4] = make_float4(Rv[4][PW-1], Rv[5][PW-1], Rv[6][PW-1], Rv[7][PW-1]);
    }
    __syncthreads();

    for (int it = 0; it < NIT; ++it) {
        const bool act = valid && (dist <= it + 1);
        float up[PW], dn[PW], lf[PH], rt[PH];
        if (act) {  // phase A: read neighbor boundaries (old values)
            if (pr > 0) {
                float4 t = *(const float4*)&bufBot[(pr-1)*SROW + c0];
                up[0]=t.x; up[1]=t.y; up[2]=t.z; up[3]=t.w;
            } else { up[0]=up[1]=up[2]=up[3]=0.f; }
            if (pr < PR-1) {
                float4 t = *(const float4*)&bufTop[(pr+1)*SROW + c0];
                dn[0]=t.x; dn[1]=t.y; dn[2]=t.z; dn[3]=t.w;
            } else { dn[0]=dn[1]=dn[2]=dn[3]=0.f; }
            if (pc > 0) {
                float4 a = *(const float4*)&bufR[(pc-1)*SCOL + r0];
                float4 e = *(const float4*)&bufR[(pc-1)*SCOL + r0 + 4];
                lf[0]=a.x; lf[1]=a.y; lf[2]=a.z; lf[3]=a.w;
                lf[4]=e.x; lf[5]=e.y; lf[6]=e.z; lf[7]=e.w;
            } else {
#pragma unroll
                for (int r = 0; r < PH; ++r) lf[r] = 0.f;
            }
            if (pc < PC-1) {
                float4 a = *(const float4*)&bufL[(pc+1)*SCOL + r0];
                float4 e = *(const float4*)&bufL[(pc+1)*SCOL + r0 + 4];
                rt[0]=a.x; rt[1]=a.y; rt[2]=a.z; rt[3]=a.w;
                rt[4]=e.x; rt[5]=e.y; rt[6]=e.z; rt[7]=e.w;
            } else {
#pragma unroll
                for (int r = 0; r < PH; ++r) rt[r] = 0.f;
            }
        }
        __syncthreads();   // all reads done before anyone overwrites
        if (act) {         // phase B: compute + publish new boundaries
            float prevOld[PW];
#pragma unroll
            for (int r = 0; r < PH; ++r) {
                float curOld[PW];
#pragma unroll
                for (int c = 0; c < PW; ++c) curOld[c] = Rv[r][c];
#pragma unroll
                for (int c = 0; c < PW; ++c) {
                    const float u  = (r > 0)    ? prevOld[c]  : up[c];
                    const float d  = (r < PH-1) ? Rv[r+1][c]  : dn[c];
                    const float l  = (c > 0)    ? curOld[c-1] : lf[r];
                    const float rr = (c < PW-1) ? curOld[c+1] : rt[r];
                    const float nb = ((u + d) + (l + rr)) * 0.25f;
                    float v = curOld[c] + nb * pv[r][c];   // contract off: mul+add
                    v = fminf(fmaxf(v, 0.0f), 1.0f);
                    Rv[r][c] = v;
                }
#pragma unroll
                for (int c = 0; c < PW; ++c) prevOld[c] = curOld[c];
            }
            *(float4*)&bufTop[pr*SROW + c0] = make_float4(Rv[0][0], Rv[0][1], Rv[0][2], Rv[0][3]);
            *(float4*)&bufBot[pr*SROW + c0] = make_float4(Rv[PH-1][0], Rv[PH-1][1], Rv[PH-1][2], Rv[PH-1][3]);
            *(float4*)&bufL[pc*SCOL + r0    ] = make_float4(Rv[0][0], Rv[1][0], Rv[2][0], Rv[3][0]);
            *(float4*)&bufL[pc*SCOL + r0 + 4] = make_float4(Rv[4][0], Rv[5][0], Rv[6][0], Rv[7][0]);
            *(float4*)&bufR[pc*SCOL + r0    ] = make_float4(Rv[0][PW-1], Rv[1][PW-1], Rv[2][PW-1], Rv[3][PW-1]);
            *(float4*)&bufR[pc*SCOL + r0 + 4] = make_float4(Rv[4][PW-1], Rv[5][PW-1], Rv[6][PW-1], Rv[7][PW-1]);
        }
        __syncthreads();   // writes visible before next read phase
    }

    // Output: goal cell value (exact 0 outside the radius-50 window).
    const int gr = min(max(goal[2*b+0], 0), H-1);
    const int gc = min(max(goal[2*b+1], 0), W-1);
    const int relr = gr - sr + RAD;
    const int relc = gc - sc + RAD;
    const bool inwin = (relr >= 0 && relr < PR*PH && relc >= 0 && relc < PC*PW);
    if (inwin) {
        if (valid && pr == (relr / PH) && pc == (relc / PW)) {
            const int lr = relr % PH;
            const int lc = relc % PW;
            float v = 0.f;
#pragma unroll
            for (int r = 0; r < PH; ++r)
#pragma unroll
                for (int c = 0; c < PW; ++c)
                    if (r == lr && c == lc) v = Rv[r][c];  // static-indexed select
            out[b] = v;
        }
    } else if (tid == 0) {
        out[b] = 0.f;
    }
}

extern "C" void kernel_launch(void* const* d_in, const int* in_sizes, int n_in,
                              void* d_out, int out_size, void* d_ws, size_t ws_size,
                              hipStream_t stream)
{
    (void)n_in; (void)out_size; (void)d_ws; (void)ws_size;
    const float* prob  = (const float*)d_in[0];
    const int*   start = (const int*)d_in[1];
    const int*   goal  = (const int*)d_in[2];
    float*       out   = (float*)d_out;

    const int B  = in_sizes[1] / 2;                   // (B,2) coords
    const long long hw = (long long)in_sizes[0] / B;  // H*W
    const int H  = (int)(sqrt((double)hw) + 0.5);
    const int W  = H;

    sbf_patch_kernel<<<dim3(B), dim3(NT), 0, stream>>>(prob, start, goal, out, H, W);
}

// Round 3
// 9.458 us; speedup vs baseline: 8.1966x; 7.8570x over previous
//
#include <hip/hip_runtime.h>
#include <math.h>

// Soft Bellman-Ford, light-cone exact version.
// Facts used (all exact, clip included — influence moves <=1 cell/iter):
//  - R0 = delta(start); support after t iters is inside L1-ball(start, t).
//    => if L1(start,goal) > 50, output is EXACTLY 0: early-exit, no work.
//  - A cell influences R_50[goal] only if d_start + d_goal <= 50, and at
//    iteration `it` (producing R_{it+1}) only if d_start <= it+1 AND
//    d_goal <= 50-(it+1). Skipping outside this cone is provably exact.
// Fallback compute: each thread owns a 4x8 register patch; LDS holds only
// inter-patch boundaries exchanged as float4.
constexpr int RAD  = 50;
constexpr int NIT  = 50;
constexpr int PW   = 4;            // patch width  (cols)
constexpr int PH   = 8;            // patch height (rows)
constexpr int PC   = 26;           // patch grid cols -> 104 cols covered
constexpr int PR   = 13;           // patch grid rows -> 104 rows covered
constexpr int NACT = PC * PR;      // 338 worker threads
constexpr int NT   = 384;          // 6 waves
constexpr int SROW = 108;          // dword stride (104+4 pad, /4 odd)
constexpr int SCOL = 108;

__global__ __launch_bounds__(NT)
void sbf_cone_kernel(const float* __restrict__ prob,
                     const int*   __restrict__ start,
                     const int*   __restrict__ goal,
                     float*       __restrict__ out,
                     int H, int W)
{
#pragma clang fp contract(off)
    __shared__ __align__(16) float bufTop[PR * SROW];
    __shared__ __align__(16) float bufBot[PR * SROW];
    __shared__ __align__(16) float bufL[PC * SCOL];
    __shared__ __align__(16) float bufR[PC * SCOL];

    const int b   = blockIdx.x;
    const int tid = threadIdx.x;

    const int sr = min(max(start[2*b+0], 0), H-1);
    const int sc = min(max(start[2*b+1], 0), W-1);
    const int gr = min(max(goal[2*b+0], 0), H-1);
    const int gc = min(max(goal[2*b+1], 0), W-1);

    // ---- Early exit: goal outside the reachable L1-ball -> exact 0. ----
    const int ddist = abs(sr - gr) + abs(sc - gc);
    if (ddist > RAD) {                 // block-uniform branch
        if (tid == 0) out[b] = 0.0f;
        return;
    }

    for (int i = tid; i < PR*SROW; i += NT) { bufTop[i] = 0.f; bufBot[i] = 0.f; }
    for (int i = tid; i < PC*SCOL; i += NT) { bufL[i]  = 0.f; bufR[i]  = 0.f; }

    const bool valid = (tid < NACT);
    const int  pr = tid / PC;
    const int  pc = tid - pr * PC;
    const int  r0 = pr * PH;           // window-relative first row
    const int  c0 = pc * PW;           // window-relative first col

    float Rv[PH][PW];
    float pv[PH][PW];
#pragma unroll
    for (int r = 0; r < PH; ++r)
#pragma unroll
        for (int c = 0; c < PW; ++c) { Rv[r][c] = 0.f; pv[r][c] = 0.f; }

    if (valid) {
        const float* pb = prob + (size_t)b * H * W;
#pragma unroll
        for (int r = 0; r < PH; ++r) {
            const int grr = sr - RAD + r0 + r;
#pragma unroll
            for (int c = 0; c < PW; ++c) {
                const int gcc = sc - RAD + c0 + c;
                // out-of-grid: p = 0 -> stays exactly 0 (SAME zero padding)
                if (grr >= 0 && grr < H && gcc >= 0 && gcc < W)
                    pv[r][c] = pb[(size_t)grr * W + gcc];
            }
        }
    }

    // R0: single 1.0 at window center (50,50).
    if (pr == RAD/PH && pc == RAD/PW) Rv[RAD%PH][RAD%PW] = 1.0f;

    // L1 distance from start (window center) to this patch's rectangle.
    const int dsr  = max(0, max(r0 - RAD, RAD - (r0 + PH - 1)));
    const int dsc  = max(0, max(c0 - RAD, RAD - (c0 + PW - 1)));
    const int dist = dsr + dsc;
    // L1 distance from goal (window-relative) to this patch's rectangle.
    const int qr = gr - sr + RAD, qc = gc - sc + RAD;   // in [0,100]
    const int dgr = max(0, max(r0 - qr, qr - (r0 + PH - 1)));
    const int dgc = max(0, max(c0 - qc, qc - (c0 + PW - 1)));
    const int distG = dgr + dgc;

    __syncthreads();   // LDS zero done

    if (valid) {       // publish R0 boundaries
        *(float4*)&bufTop[pr*SROW + c0] = make_float4(Rv[0][0], Rv[0][1], Rv[0][2], Rv[0][3]);
        *(float4*)&bufBot[pr*SROW + c0] = make_float4(Rv[PH-1][0], Rv[PH-1][1], Rv[PH-1][2], Rv[PH-1][3]);
        *(float4*)&bufL[pc*SCOL + r0    ] = make_float4(Rv[0][0], Rv[1][0], Rv[2][0], Rv[3][0]);
        *(float4*)&bufL[pc*SCOL + r0 + 4] = make_float4(Rv[4][0], Rv[5][0], Rv[6][0], Rv[7][0]);
        *(float4*)&bufR[pc*SCOL + r0    ] = make_float4(Rv[0][PW-1], Rv[1][PW-1], Rv[2][PW-1], Rv[3][PW-1]);
        *(float4*)&bufR[pc*SCOL + r0 + 4] = make_float4(Rv[4][PW-1], Rv[5][PW-1], Rv[6][PW-1], Rv[7][PW-1]);
    }
    __syncthreads();

    for (int it = 0; it < NIT; ++it) {
        // Light-cone gate: value can be nonzero only if dist <= it+1;
        // it can still influence the goal only if distG <= NIT-(it+1).
        const bool act = valid && (dist <= it + 1) && (distG <= NIT - (it + 1));
        float up[PW], dn[PW], lf[PH], rt[PH];
        if (act) {  // phase A: read neighbor boundaries (old values)
            if (pr > 0) {
                float4 t = *(const float4*)&bufBot[(pr-1)*SROW + c0];
                up[0]=t.x; up[1]=t.y; up[2]=t.z; up[3]=t.w;
            } else { up[0]=up[1]=up[2]=up[3]=0.f; }
            if (pr < PR-1) {
                float4 t = *(const float4*)&bufTop[(pr+1)*SROW + c0];
                dn[0]=t.x; dn[1]=t.y; dn[2]=t.z; dn[3]=t.w;
            } else { dn[0]=dn[1]=dn[2]=dn[3]=0.f; }
            if (pc > 0) {
                float4 a = *(const float4*)&bufR[(pc-1)*SCOL + r0];
                float4 e = *(const float4*)&bufR[(pc-1)*SCOL + r0 + 4];
                lf[0]=a.x; lf[1]=a.y; lf[2]=a.z; lf[3]=a.w;
                lf[4]=e.x; lf[5]=e.y; lf[6]=e.z; lf[7]=e.w;
            } else {
#pragma unroll
                for (int r = 0; r < PH; ++r) lf[r] = 0.f;
            }
            if (pc < PC-1) {
                float4 a = *(const float4*)&bufL[(pc+1)*SCOL + r0];
                float4 e = *(const float4*)&bufL[(pc+1)*SCOL + r0 + 4];
                rt[0]=a.x; rt[1]=a.y; rt[2]=a.z; rt[3]=a.w;
                rt[4]=e.x; rt[5]=e.y; rt[6]=e.z; rt[7]=e.w;
            } else {
#pragma unroll
                for (int r = 0; r < PH; ++r) rt[r] = 0.f;
            }
        }
        __syncthreads();   // all reads done before anyone overwrites
        if (act) {         // phase B: compute + publish new boundaries
            float prevOld[PW];
#pragma unroll
            for (int r = 0; r < PH; ++r) {
                float curOld[PW];
#pragma unroll
                for (int c = 0; c < PW; ++c) curOld[c] = Rv[r][c];
#pragma unroll
                for (int c = 0; c < PW; ++c) {
                    const float u  = (r > 0)    ? prevOld[c]  : up[c];
                    const float d  = (r < PH-1) ? Rv[r+1][c]  : dn[c];
                    const float l  = (c > 0)    ? curOld[c-1] : lf[r];
                    const float rr = (c < PW-1) ? curOld[c+1] : rt[r];
                    const float nb = ((u + d) + (l + rr)) * 0.25f;
                    float v = curOld[c] + nb * pv[r][c];   // contract off
                    v = fminf(fmaxf(v, 0.0f), 1.0f);
                    Rv[r][c] = v;
                }
#pragma unroll
                for (int c = 0; c < PW; ++c) prevOld[c] = curOld[c];
            }
            *(float4*)&bufTop[pr*SROW + c0] = make_float4(Rv[0][0], Rv[0][1], Rv[0][2], Rv[0][3]);
            *(float4*)&bufBot[pr*SROW + c0] = make_float4(Rv[PH-1][0], Rv[PH-1][1], Rv[PH-1][2], Rv[PH-1][3]);
            *(float4*)&bufL[pc*SCOL + r0    ] = make_float4(Rv[0][0], Rv[1][0], Rv[2][0], Rv[3][0]);
            *(float4*)&bufL[pc*SCOL + r0 + 4] = make_float4(Rv[4][0], Rv[5][0], Rv[6][0], Rv[7][0]);
            *(float4*)&bufR[pc*SCOL + r0    ] = make_float4(Rv[0][PW-1], Rv[1][PW-1], Rv[2][PW-1], Rv[3][PW-1]);
            *(float4*)&bufR[pc*SCOL + r0 + 4] = make_float4(Rv[4][PW-1], Rv[5][PW-1], Rv[6][PW-1], Rv[7][PW-1]);
        }
        __syncthreads();
    }

    // Output: goal is guaranteed inside the window here (ddist <= 50).
    if (valid && pr == (qr / PH) && pc == (qc / PW)) {
        const int lr = qr % PH;
        const int lc = qc % PW;
        float v = 0.f;
#pragma unroll
        for (int r = 0; r < PH; ++r)
#pragma unroll
            for (int c = 0; c < PW; ++c)
                if (r == lr && c == lc) v = Rv[r][c];  // static-indexed select
        out[b] = v;
    }
}

extern "C" void kernel_launch(void* const* d_in, const int* in_sizes, int n_in,
                              void* d_out, int out_size, void* d_ws, size_t ws_size,
                              hipStream_t stream)
{
    (void)n_in; (void)out_size; (void)d_ws; (void)ws_size;
    const float* prob  = (const float*)d_in[0];
    const int*   start = (const int*)d_in[1];
    const int*   goal  = (const int*)d_in[2];
    float*       out   = (float*)d_out;

    const int B  = in_sizes[1] / 2;                   // (B,2) coords
    const long long hw = (long long)in_sizes[0] / B;  // H*W
    const int H  = (int)(sqrt((double)hw) + 0.5);
    const int W  = H;

    sbf_cone_kernel<<<dim3(B), dim3(NT), 0, stream>>>(prob, start, goal, out, H, W);
}